// Round 11
// baseline (261.962 us; speedup 1.0000x reference)
//
#include <hip/hip_runtime.h>

typedef __attribute__((ext_vector_type(4))) float f32x4;
typedef __attribute__((ext_vector_type(8))) short s16x8;
typedef __attribute__((ext_vector_type(4))) short s16x4;
typedef __bf16 bf16x4 __attribute__((ext_vector_type(4)));

#define B_   96
#define NQ   35
#define LP   180
#define H_   768
#define D_   128
#define NEGF (-1e30f)

#define NROWS 37920
#define QROWS 3360
#define PROWS 17280

__device__ __forceinline__ unsigned short f2bf(float f) {
    return __builtin_bit_cast(unsigned short, (__bf16)f);
}

__device__ __forceinline__ s16x4 cvt_bf4(f32x4 v) {
    return __builtin_bit_cast(s16x4, __builtin_convertvector(v, bf16x4));
}

__device__ __forceinline__ s16x8 pack_bf16(f32x4 v0, f32x4 v1) {
    bf16x4 h0 = __builtin_convertvector(v0, bf16x4);
    bf16x4 h1 = __builtin_convertvector(v1, bf16x4);
    s16x4 a = __builtin_bit_cast(s16x4, h0), b = __builtin_bit_cast(s16x4, h1);
    return __builtin_shufflevector(a, b, 0, 1, 2, 3, 4, 5, 6, 7);
}

// async global->LDS, 16 B per lane; lds dest must be wave-uniform (HW adds lane*16)
__device__ __forceinline__ void glds16(const void* g, void* l) {
    __builtin_amdgcn_global_load_lds(
        (const __attribute__((address_space(1))) unsigned int*)g,
        (__attribute__((address_space(3))) unsigned int*)l,
        16, 0, 0);
}

// ---------------- prep: wt_build (blocks 0-47) + ssq zero (48-191) + mask detect (192) ----
__global__ __launch_bounds__(256) void prep_k(
    const float* __restrict__ W, unsigned short* __restrict__ wthi,
    const unsigned int* __restrict__ pmask_w, unsigned int* __restrict__ ctrl,
    float* __restrict__ ssq) {
    __shared__ unsigned int rr[256];
    int b = blockIdx.x, t = threadIdx.x;
    if (b < 48) {
        int tid = b * 256 + t;
        int nt = tid / (24 * 64);
        int r = tid - nt * 24 * 64;
        int ks = r / 64, lane = r - ks * 64;
        int m = lane & 15, quad = lane >> 4;
        unsigned short* o = wthi + (size_t)tid * 8;
#pragma unroll
        for (int j = 0; j < 8; j++) {
            int k = ks * 32 + quad * 8 + j;
            o[j] = f2bf(W[(size_t)k * D_ + nt * 16 + m]);
        }
    } else if (b < 192) {
        ssq[(b - 48) * 256 + t] = 0.f;       // 144*256 = 36864 exactly
    } else {
        unsigned int f1 = 0, f3 = 0, f4 = 0;
        for (int w = t; w < 4320; w += 256) {
            unsigned int v = pmask_w[w];
            f1 |= v & 0x0000ff00u;                 // byte %4==1 -> 1-byte layout
            f3 |= v & 0xff000000u;                 // byte %4==3 -> float32
            if (w & 1) f4 |= v & 0x000000ffu;      // byte %8==4 -> int32
        }
        rr[t] = f1; __syncthreads();
        for (int s2 = 128; s2; s2 >>= 1) { if (t < s2) rr[t] |= rr[t + s2]; __syncthreads(); }
        if (!t) ctrl[0] = rr[0];
        __syncthreads();
        rr[t] = f3; __syncthreads();
        for (int s2 = 128; s2; s2 >>= 1) { if (t < s2) rr[t] |= rr[t + s2]; __syncthreads(); }
        if (!t) ctrl[1] = rr[0];
        __syncthreads();
        rr[t] = f4; __syncthreads();
        for (int s2 = 128; s2; s2 >>= 1) { if (t < s2) rr[t] |= rr[t + s2]; __syncthreads(); }
        if (!t) ctrl[2] = rr[0];
    }
}

// ---------------- proj v4: dense A stream, bf16-on-write LDS transpose, 2-deep prefetch --
__global__ __launch_bounds__(256) void proj_k(
    const float* __restrict__ qh, const float* __restrict__ ph, const float* __restrict__ nh,
    const unsigned short* __restrict__ wthi, const float* __restrict__ bias,
    float* __restrict__ x, float* __restrict__ ssq,
    const void* __restrict__ pm, const void* __restrict__ nm,
    const unsigned int* __restrict__ ctrl, unsigned char* __restrict__ maskc) {
    // ushort units: row stride 40 (80 B), ksg stride 640, mt stride 1280, buf stride 2560
    __shared__ unsigned short sh[5120];              // 10240 B
    int b = blockIdx.x;
    if (b >= 1185) {                                 // ---- mask canon: 135 blocks exact ----
        int i = (b - 1185) * 256 + threadIdx.x;      // < 34560
        const void* src = (i < B_ * LP) ? pm : nm;
        int j = (i < B_ * LP) ? i : i - B_ * LP;
        unsigned int c1 = ctrl[0], c3 = ctrl[1], c4 = ctrl[2];
        bool bit;
        if (c1 > 0)       bit = ((const unsigned char*)src)[j] != 0;
        else if (c3 > 0)  bit = ((const float*)src)[j] != 0.0f;
        else if (c4 > 0)  bit = ((const int*)src)[j] != 0;
        else              bit = ((const long long*)src)[j] != 0;
        maskc[i] = bit ? 1 : 0;
        return;
    }
    int t = threadIdx.x;
    int wave = t >> 6, lane = t & 63;
    const float* src; int row0l; int growbase;
    if (b < 105)      { src = qh; row0l = b * 32;         growbase = row0l; }
    else if (b < 645) { src = ph; row0l = (b - 105) * 32; growbase = QROWS + row0l; }
    else              { src = nh; row0l = (b - 645) * 32; growbase = QROWS + PROWS + row0l; }
    int m = lane & 15, quad = lane >> 4;

    int srow = t >> 4, c = t & 15;
    int sksg = c >> 3, kk = c & 7;
    int woff0 = sksg * 640 + srow * 40 + kk * 4;     // mt = 0
    int woff1 = woff0 + 1280;                        // mt = 1
    int roff = m * 40 + quad * 8;
    const float* gp0 = src + (size_t)(row0l + srow) * H_ + c * 4;
    const float* gp1 = gp0 + (size_t)16 * H_;

    f32x4 acc[2][2];
#pragma unroll
    for (int mt = 0; mt < 2; mt++)
#pragma unroll
        for (int ntl = 0; ntl < 2; ntl++) acc[mt][ntl] = (f32x4){0.f, 0.f, 0.f, 0.f};

    int nt0 = wave * 2, nt1 = wave * 2 + 1;

    // 2-deep register prefetch
    f32x4 pvA0 = *(const f32x4*)gp0;
    f32x4 pvA1 = *(const f32x4*)gp1;
    f32x4 pvB0 = *(const f32x4*)(gp0 + 64);
    f32x4 pvB1 = *(const f32x4*)(gp1 + 64);

#pragma unroll 2
    for (int s = 0; s < 12; s++) {
        int bufo = (s & 1) * 2560;
        *(s16x4*)&sh[bufo + woff0] = cvt_bf4(pvA0);
        *(s16x4*)&sh[bufo + woff1] = cvt_bf4(pvA1);
        __syncthreads();
        pvA0 = pvB0; pvA1 = pvB1;
        if (s < 10) {
            pvB0 = *(const f32x4*)(gp0 + (s + 2) * 64);
            pvB1 = *(const f32x4*)(gp1 + (s + 2) * 64);
        }
#pragma unroll
        for (int ksg = 0; ksg < 2; ksg++) {
            int ksgg = s * 2 + ksg;
            s16x8 a0 = *(const s16x8*)&sh[bufo + ksg * 640 + roff];
            s16x8 a1 = *(const s16x8*)&sh[bufo + ksg * 640 + 1280 + roff];
            s16x8 bh0 = *(const s16x8*)(wthi + ((size_t)(nt0 * 24 + ksgg) * 64 + lane) * 8);
            s16x8 bh1 = *(const s16x8*)(wthi + ((size_t)(nt1 * 24 + ksgg) * 64 + lane) * 8);
            acc[0][0] = __builtin_amdgcn_mfma_f32_16x16x32_bf16(a0, bh0, acc[0][0], 0, 0, 0);
            acc[0][1] = __builtin_amdgcn_mfma_f32_16x16x32_bf16(a0, bh1, acc[0][1], 0, 0, 0);
            acc[1][0] = __builtin_amdgcn_mfma_f32_16x16x32_bf16(a1, bh0, acc[1][0], 0, 0, 0);
            acc[1][1] = __builtin_amdgcn_mfma_f32_16x16x32_bf16(a1, bh1, acc[1][1], 0, 0, 0);
        }
    }

    // epilogue: x write + fused ssq
#pragma unroll
    for (int mt = 0; mt < 2; mt++) {
        int base = growbase + mt * 16;
        int bk0, bk1, b1start;
        if (base < QROWS)              { bk0 = base / 35;  bk1 = (base + 15) / 35;
                                         b1start = bk1 * 35; }
        else if (base < QROWS + PROWS) { int r0 = base - QROWS;
                                         bk0 = 96 + r0 / 180;  bk1 = 96 + (r0 + 15) / 180;
                                         b1start = QROWS + (bk1 - 96) * 180; }
        else                           { int r0 = base - QROWS - PROWS;
                                         bk0 = 192 + r0 / 180; bk1 = 192 + (r0 + 15) / 180;
                                         b1start = QROWS + PROWS + (bk1 - 192) * 180; }
#pragma unroll
        for (int ntl = 0; ntl < 2; ntl++) {
            int col = (wave * 2 + ntl) * 16 + m;
            float bv = bias[col];
            f32x4 s4 = acc[mt][ntl];
            float slo = 0.f, shi = 0.f;
#pragma unroll
            for (int r = 0; r < 4; r++) {
                int grow = base + quad * 4 + r;
                float v = s4[r] + bv;
                x[(size_t)grow * D_ + col] = v;
                float v2 = v * v;
                if (bk1 > bk0 && grow >= b1start) shi += v2; else slo += v2;
            }
            slo += __shfl_xor(slo, 16); slo += __shfl_xor(slo, 32);
            if (quad == 0) atomicAdd(ssq + (size_t)bk0 * D_ + col, slo);
            if (bk1 > bk0) {
                shi += __shfl_xor(shi, 16); shi += __shfl_xor(shi, 32);
                if (quad == 0) atomicAdd(ssq + (size_t)bk1 * D_ + col, shi);
            }
        }
    }
}

// ---------------- scatter v2: dense read -> LDS transpose -> dense frag write ----------
// Block = one 16-row x 128-col tile (g<240: qfrag tile (qp,mt); else pfrag tile (pbk,nt)).
// Phase 1: thread t reads row (t>>4) [gathered via mask for p], 32 contiguous bytes at
// d0=(t&15)*8, scales by rsqrt(ssq), packs bf16, stores to padded LDS. Phase 2: thread t
// reads its frag chunk from LDS and writes 16 B to a fully-contiguous 4 KB global region.
__global__ __launch_bounds__(256) void scatter_k(
    const float* __restrict__ x, const float* __restrict__ ssq,
    const unsigned char* __restrict__ maskc,
    unsigned short* __restrict__ qfrag, unsigned short* __restrict__ pfrag) {
    __shared__ unsigned short sh[16 * 136];          // row stride 136 ushorts (272 B)
    int g = blockIdx.x;                              // 2544
    int t = threadIdx.x;
    int srow = t >> 4, c16 = t & 15;
    int d0 = c16 * 8;

    s16x8 v8 = (s16x8){0, 0, 0, 0, 0, 0, 0, 0};
    if (g < 240) {
        int mt = g % 5, qp = g / 5;
        int prow = mt * 16 + srow;
        if (prow < 70) {
            int hi = prow >= 35;
            int bq = qp * 2 + hi;
            int l = prow - hi * 35;
            size_t row = (size_t)bq * 35 + l;
            const f32x4* px = (const f32x4*)(x + row * D_ + d0);
            f32x4 v0 = px[0], v1 = px[1];
            const f32x4* pq = (const f32x4*)(ssq + (size_t)bq * D_ + d0);
            f32x4 q0 = pq[0], q1 = pq[1];
            f32x4 r0, r1;
#pragma unroll
            for (int j = 0; j < 4; j++) {
                r0[j] = rsqrtf(fmaxf(q0[j], 1e-24f));
                r1[j] = rsqrtf(fmaxf(q1[j], 1e-24f));
            }
            v8 = pack_bf16(v0 * r0, v1 * r1);
        }
    } else {
        int g2 = g - 240;
        int nt = g2 % 12, pbk = g2 / 12;
        int l = nt * 16 + srow;
        int lsrc = (l < LP && maskc[pbk * LP + l]) ? l : 0;
        size_t row = QROWS + (size_t)pbk * LP + lsrc;
        const f32x4* px = (const f32x4*)(x + row * D_ + d0);
        f32x4 v0 = px[0], v1 = px[1];
        const f32x4* pq = (const f32x4*)(ssq + (size_t)(96 + pbk) * D_ + d0);
        f32x4 q0 = pq[0], q1 = pq[1];
        f32x4 r0, r1;
#pragma unroll
        for (int j = 0; j < 4; j++) {
            r0[j] = rsqrtf(fmaxf(q0[j], 1e-24f));
            r1[j] = rsqrtf(fmaxf(q1[j], 1e-24f));
        }
        v8 = pack_bf16(v0 * r0, v1 * r1);
    }
    *(s16x8*)&sh[srow * 136 + d0] = v8;              // byte ofs = srow*272 + c16*16, aligned
    __syncthreads();

    int ks = t >> 6, lane = t & 63;
    int mm = lane & 15, quad = lane >> 4;
    s16x8 o = *(const s16x8*)&sh[mm * 136 + ks * 32 + quad * 8];
    unsigned short* dst = (g < 240) ? (qfrag + (size_t)g * 2048)
                                    : (pfrag + (size_t)(g - 240) * 2048);
    *(s16x8*)(dst + (size_t)t * 8) = o;              // 4 KB contiguous per block
}

// ---------------- interact v3: 768 blocks, 3 qp per wave, p staged once per 12 qp -------
__global__ __launch_bounds__(256, 3) void interact_k(
    const unsigned short* __restrict__ qfrag, const unsigned short* __restrict__ pfrag,
    float* __restrict__ out) {
    __shared__ unsigned short plds[24576];           // 48 KB, shared by all 4 waves
    int wave = threadIdx.x >> 6, lane = threadIdx.x & 63;
    int b = blockIdx.x;                              // 768 blocks = 3/CU, one round
    int xcd = b & 7, i = b >> 3;                     // i in [0,96)
    int c = xcd * 24 + (i % 24);                     // [0,192), pinned per XCD
    int qg = i / 24;                                 // [0,4)
    int side = c / 96, pb = c - side * 96;
    int m = lane & 15, quad = lane >> 4;

    const unsigned short* pbase = pfrag + (size_t)c * 24576;

    // stage the 48 KB p-block (wave stages nt = wave*3 .. +3)
#pragma unroll
    for (int ntl = 0; ntl < 3; ntl++) {
        int nt = wave * 3 + ntl;
#pragma unroll
        for (int ks = 0; ks < 4; ks++)
            glds16(pbase + ((size_t)(nt * 4 + ks) * 64 + lane) * 8,
                   &plds[(size_t)(nt * 4 + ks) * 512]);
    }
    __syncthreads();                                 // drain staging

    const f32x4 zero4 = (f32x4){0.f, 0.f, 0.f, 0.f};

    for (int qpi = 0; qpi < 3; qpi++) {
        int qp = qg * 12 + wave * 3 + qpi;
        const unsigned short* qbase = qfrag + (size_t)qp * 10240;

        s16x8 a[5][4];
#pragma unroll
        for (int mt = 0; mt < 5; mt++)
#pragma unroll
            for (int ks = 0; ks < 4; ks++)
                a[mt][ks] = *(const s16x8*)(qbase + ((size_t)(mt * 4 + ks) * 64 + lane) * 8);

        float rmax[5][4];
#pragma unroll
        for (int mt = 0; mt < 5; mt++)
#pragma unroll
            for (int rr = 0; rr < 4; rr++) rmax[mt][rr] = NEGF;

        for (int nt = 0; nt < 12; nt++) {
            s16x8 bfr[4];
#pragma unroll
            for (int ks = 0; ks < 4; ks++)
                bfr[ks] = *(const s16x8*)&plds[((size_t)(nt * 4 + ks) * 64 + lane) * 8];
#pragma unroll
            for (int mt = 0; mt < 5; mt++) {
                f32x4 acc = __builtin_amdgcn_mfma_f32_16x16x32_bf16(a[mt][0], bfr[0], zero4, 0, 0, 0);
                acc = __builtin_amdgcn_mfma_f32_16x16x32_bf16(a[mt][1], bfr[1], acc, 0, 0, 0);
                acc = __builtin_amdgcn_mfma_f32_16x16x32_bf16(a[mt][2], bfr[2], acc, 0, 0, 0);
                acc = __builtin_amdgcn_mfma_f32_16x16x32_bf16(a[mt][3], bfr[3], acc, 0, 0, 0);
#pragma unroll
                for (int rr = 0; rr < 4; rr++)
                    rmax[mt][rr] = fmaxf(rmax[mt][rr], acc[rr]);
            }
        }

#pragma unroll
        for (int mt = 0; mt < 5; mt++)
#pragma unroll
            for (int rr = 0; rr < 4; rr++) {
                float v = rmax[mt][rr];
                v = fmaxf(v, __shfl_xor(v, 1));
                v = fmaxf(v, __shfl_xor(v, 2));
                v = fmaxf(v, __shfl_xor(v, 4));
                v = fmaxf(v, __shfl_xor(v, 8));
                rmax[mt][rr] = v;
            }
        float s0 = 0.f, s1 = 0.f;
#pragma unroll
        for (int mt = 0; mt < 5; mt++)
#pragma unroll
            for (int rr = 0; rr < 4; rr++) {
                int prow = mt * 16 + quad * 4 + rr;
                float v = rmax[mt][rr];
                if (prow < 35) s0 += v;
                else if (prow < 70) s1 += v;
            }
        s0 += __shfl_xor(s0, 16); s0 += __shfl_xor(s0, 32);
        s1 += __shfl_xor(s1, 16); s1 += __shfl_xor(s1, 32);
        if (lane == 0) {
            int qb0 = qp * 2, qb1 = qp * 2 + 1;
            out[(size_t)qb0 * (2 * B_) + side * B_ + pb] = s0;
            out[(size_t)qb1 * (2 * B_) + side * B_ + pb] = s1;
        }
    }
}

// ---------------- launch ----------------
extern "C" void kernel_launch(void* const* d_in, const int* in_sizes, int n_in,
                              void* d_out, int out_size, void* d_ws, size_t ws_size,
                              hipStream_t stream) {
    const float* qh   = (const float*)d_in[0];
    const float* ph   = (const float*)d_in[1];
    const float* nh   = (const float*)d_in[2];
    const float* W    = (const float*)d_in[3];
    const float* bias = (const float*)d_in[4];
    const void* pmask = d_in[5];
    const void* nmask = d_in[6];
    float* out = (float*)d_out;
    char* ws = (char*)d_ws;

    constexpr size_t CTRL_OFF  = 0;                          // 256 B
    constexpr size_t WTHI_OFF  = 256;                        // 196608 B
    constexpr size_t MASKC_OFF = WTHI_OFF + 196608;          // 34560 B -> ends 231424
    constexpr size_t SSQ_OFF   = 231424;                     // 147456 B
    constexpr size_t X_OFF     = SSQ_OFF + 147456;           // 19415040 B
    constexpr size_t QFRAG_OFF = X_OFF + (size_t)NROWS * D_ * 4;   // 983040 B
    constexpr size_t PFRAG_OFF = QFRAG_OFF + 983040;         // 9437184 B

    unsigned int* ctrl     = (unsigned int*)(ws + CTRL_OFF);
    unsigned short* wthi   = (unsigned short*)(ws + WTHI_OFF);
    unsigned char* maskc   = (unsigned char*)(ws + MASKC_OFF);
    float* ssq             = (float*)(ws + SSQ_OFF);
    float* x               = (float*)(ws + X_OFF);
    unsigned short* qfrag  = (unsigned short*)(ws + QFRAG_OFF);
    unsigned short* pfrag  = (unsigned short*)(ws + PFRAG_OFF);

    prep_k<<<193, 256, 0, stream>>>(W, wthi, (const unsigned int*)pmask, ctrl, ssq);
    proj_k<<<1185 + 135, 256, 0, stream>>>(qh, ph, nh, wthi, bias, x, ssq,
                                           pmask, nmask, ctrl, maskc);
    scatter_k<<<2544, 256, 0, stream>>>(x, ssq, maskc, qfrag, pfrag);
    interact_k<<<768, 256, 0, stream>>>(qfrag, pfrag, out);
}

// Round 12
// 209.606 us; speedup vs baseline: 1.2498x; 1.2498x over previous
//
#include <hip/hip_runtime.h>

typedef __attribute__((ext_vector_type(4))) float f32x4;
typedef __attribute__((ext_vector_type(8))) short s16x8;
typedef __attribute__((ext_vector_type(4))) short s16x4;
typedef __bf16 bf16x4 __attribute__((ext_vector_type(4)));

#define B_   96
#define NQ   35
#define LP   180
#define H_   768
#define D_   128
#define NEGF (-1e30f)

#define NROWS 37920
#define QROWS 3360
#define PROWS 17280

__device__ __forceinline__ unsigned short f2bf(float f) {
    return __builtin_bit_cast(unsigned short, (__bf16)f);
}

__device__ __forceinline__ s16x4 cvt_bf4(f32x4 v) {
    return __builtin_bit_cast(s16x4, __builtin_convertvector(v, bf16x4));
}

__device__ __forceinline__ s16x8 pack_bf16(f32x4 v0, f32x4 v1) {
    bf16x4 h0 = __builtin_convertvector(v0, bf16x4);
    bf16x4 h1 = __builtin_convertvector(v1, bf16x4);
    s16x4 a = __builtin_bit_cast(s16x4, h0), b = __builtin_bit_cast(s16x4, h1);
    return __builtin_shufflevector(a, b, 0, 1, 2, 3, 4, 5, 6, 7);
}

// async global->LDS, 16 B per lane; lds dest must be wave-uniform (HW adds lane*16)
__device__ __forceinline__ void glds16(const void* g, void* l) {
    __builtin_amdgcn_global_load_lds(
        (const __attribute__((address_space(1))) unsigned int*)g,
        (__attribute__((address_space(3))) unsigned int*)l,
        16, 0, 0);
}

// ---------------- prep: wt_build (blocks 0-47) + ssq zero (48-191) + mask detect (192) ----
__global__ __launch_bounds__(256) void prep_k(
    const float* __restrict__ W, unsigned short* __restrict__ wthi,
    const unsigned int* __restrict__ pmask_w, unsigned int* __restrict__ ctrl,
    float* __restrict__ ssq) {
    __shared__ unsigned int rr[256];
    int b = blockIdx.x, t = threadIdx.x;
    if (b < 48) {
        int tid = b * 256 + t;
        int nt = tid / (24 * 64);
        int r = tid - nt * 24 * 64;
        int ks = r / 64, lane = r - ks * 64;
        int m = lane & 15, quad = lane >> 4;
        unsigned short* o = wthi + (size_t)tid * 8;
#pragma unroll
        for (int j = 0; j < 8; j++) {
            int k = ks * 32 + quad * 8 + j;
            o[j] = f2bf(W[(size_t)k * D_ + nt * 16 + m]);
        }
    } else if (b < 192) {
        ssq[(b - 48) * 256 + t] = 0.f;       // 144*256 = 36864 exactly
    } else {
        unsigned int f1 = 0, f3 = 0, f4 = 0;
        for (int w = t; w < 4320; w += 256) {
            unsigned int v = pmask_w[w];
            f1 |= v & 0x0000ff00u;                 // byte %4==1 -> 1-byte layout
            f3 |= v & 0xff000000u;                 // byte %4==3 -> float32
            if (w & 1) f4 |= v & 0x000000ffu;      // byte %8==4 -> int32
        }
        rr[t] = f1; __syncthreads();
        for (int s2 = 128; s2; s2 >>= 1) { if (t < s2) rr[t] |= rr[t + s2]; __syncthreads(); }
        if (!t) ctrl[0] = rr[0];
        __syncthreads();
        rr[t] = f3; __syncthreads();
        for (int s2 = 128; s2; s2 >>= 1) { if (t < s2) rr[t] |= rr[t + s2]; __syncthreads(); }
        if (!t) ctrl[1] = rr[0];
        __syncthreads();
        rr[t] = f4; __syncthreads();
        for (int s2 = 128; s2; s2 >>= 1) { if (t < s2) rr[t] |= rr[t + s2]; __syncthreads(); }
        if (!t) ctrl[2] = rr[0];
    }
}

// ---------------- proj v4: dense A stream, bf16-on-write LDS transpose, 2-deep prefetch --
__global__ __launch_bounds__(256) void proj_k(
    const float* __restrict__ qh, const float* __restrict__ ph, const float* __restrict__ nh,
    const unsigned short* __restrict__ wthi, const float* __restrict__ bias,
    float* __restrict__ x, float* __restrict__ ssq,
    const void* __restrict__ pm, const void* __restrict__ nm,
    const unsigned int* __restrict__ ctrl, unsigned char* __restrict__ maskc) {
    // ushort units: row stride 40 (80 B), ksg stride 640, mt stride 1280, buf stride 2560
    __shared__ unsigned short sh[5120];              // 10240 B
    int b = blockIdx.x;
    if (b >= 1185) {                                 // ---- mask canon: 135 blocks exact ----
        int i = (b - 1185) * 256 + threadIdx.x;      // < 34560
        const void* src = (i < B_ * LP) ? pm : nm;
        int j = (i < B_ * LP) ? i : i - B_ * LP;
        unsigned int c1 = ctrl[0], c3 = ctrl[1], c4 = ctrl[2];
        bool bit;
        if (c1 > 0)       bit = ((const unsigned char*)src)[j] != 0;
        else if (c3 > 0)  bit = ((const float*)src)[j] != 0.0f;
        else if (c4 > 0)  bit = ((const int*)src)[j] != 0;
        else              bit = ((const long long*)src)[j] != 0;
        maskc[i] = bit ? 1 : 0;
        return;
    }
    int t = threadIdx.x;
    int wave = t >> 6, lane = t & 63;
    const float* src; int row0l; int growbase;
    if (b < 105)      { src = qh; row0l = b * 32;         growbase = row0l; }
    else if (b < 645) { src = ph; row0l = (b - 105) * 32; growbase = QROWS + row0l; }
    else              { src = nh; row0l = (b - 645) * 32; growbase = QROWS + PROWS + row0l; }
    int m = lane & 15, quad = lane >> 4;

    int srow = t >> 4, c = t & 15;
    int sksg = c >> 3, kk = c & 7;
    int woff0 = sksg * 640 + srow * 40 + kk * 4;     // mt = 0
    int woff1 = woff0 + 1280;                        // mt = 1
    int roff = m * 40 + quad * 8;
    const float* gp0 = src + (size_t)(row0l + srow) * H_ + c * 4;
    const float* gp1 = gp0 + (size_t)16 * H_;

    f32x4 acc[2][2];
#pragma unroll
    for (int mt = 0; mt < 2; mt++)
#pragma unroll
        for (int ntl = 0; ntl < 2; ntl++) acc[mt][ntl] = (f32x4){0.f, 0.f, 0.f, 0.f};

    int nt0 = wave * 2, nt1 = wave * 2 + 1;

    // 2-deep register prefetch
    f32x4 pvA0 = *(const f32x4*)gp0;
    f32x4 pvA1 = *(const f32x4*)gp1;
    f32x4 pvB0 = *(const f32x4*)(gp0 + 64);
    f32x4 pvB1 = *(const f32x4*)(gp1 + 64);

#pragma unroll 2
    for (int s = 0; s < 12; s++) {
        int bufo = (s & 1) * 2560;
        *(s16x4*)&sh[bufo + woff0] = cvt_bf4(pvA0);
        *(s16x4*)&sh[bufo + woff1] = cvt_bf4(pvA1);
        __syncthreads();
        pvA0 = pvB0; pvA1 = pvB1;
        if (s < 10) {
            pvB0 = *(const f32x4*)(gp0 + (s + 2) * 64);
            pvB1 = *(const f32x4*)(gp1 + (s + 2) * 64);
        }
#pragma unroll
        for (int ksg = 0; ksg < 2; ksg++) {
            int ksgg = s * 2 + ksg;
            s16x8 a0 = *(const s16x8*)&sh[bufo + ksg * 640 + roff];
            s16x8 a1 = *(const s16x8*)&sh[bufo + ksg * 640 + 1280 + roff];
            s16x8 bh0 = *(const s16x8*)(wthi + ((size_t)(nt0 * 24 + ksgg) * 64 + lane) * 8);
            s16x8 bh1 = *(const s16x8*)(wthi + ((size_t)(nt1 * 24 + ksgg) * 64 + lane) * 8);
            acc[0][0] = __builtin_amdgcn_mfma_f32_16x16x32_bf16(a0, bh0, acc[0][0], 0, 0, 0);
            acc[0][1] = __builtin_amdgcn_mfma_f32_16x16x32_bf16(a0, bh1, acc[0][1], 0, 0, 0);
            acc[1][0] = __builtin_amdgcn_mfma_f32_16x16x32_bf16(a1, bh0, acc[1][0], 0, 0, 0);
            acc[1][1] = __builtin_amdgcn_mfma_f32_16x16x32_bf16(a1, bh1, acc[1][1], 0, 0, 0);
        }
    }

    // epilogue: x write + fused ssq
#pragma unroll
    for (int mt = 0; mt < 2; mt++) {
        int base = growbase + mt * 16;
        int bk0, bk1, b1start;
        if (base < QROWS)              { bk0 = base / 35;  bk1 = (base + 15) / 35;
                                         b1start = bk1 * 35; }
        else if (base < QROWS + PROWS) { int r0 = base - QROWS;
                                         bk0 = 96 + r0 / 180;  bk1 = 96 + (r0 + 15) / 180;
                                         b1start = QROWS + (bk1 - 96) * 180; }
        else                           { int r0 = base - QROWS - PROWS;
                                         bk0 = 192 + r0 / 180; bk1 = 192 + (r0 + 15) / 180;
                                         b1start = QROWS + PROWS + (bk1 - 192) * 180; }
#pragma unroll
        for (int ntl = 0; ntl < 2; ntl++) {
            int col = (wave * 2 + ntl) * 16 + m;
            float bv = bias[col];
            f32x4 s4 = acc[mt][ntl];
            float slo = 0.f, shi = 0.f;
#pragma unroll
            for (int r = 0; r < 4; r++) {
                int grow = base + quad * 4 + r;
                float v = s4[r] + bv;
                x[(size_t)grow * D_ + col] = v;
                float v2 = v * v;
                if (bk1 > bk0 && grow >= b1start) shi += v2; else slo += v2;
            }
            slo += __shfl_xor(slo, 16); slo += __shfl_xor(slo, 32);
            if (quad == 0) atomicAdd(ssq + (size_t)bk0 * D_ + col, slo);
            if (bk1 > bk0) {
                shi += __shfl_xor(shi, 16); shi += __shfl_xor(shi, 32);
                if (quad == 0) atomicAdd(ssq + (size_t)bk1 * D_ + col, shi);
            }
        }
    }
}

// ---------------- scatter v2: dense read -> LDS transpose -> dense frag write ----------
__global__ __launch_bounds__(256) void scatter_k(
    const float* __restrict__ x, const float* __restrict__ ssq,
    const unsigned char* __restrict__ maskc,
    unsigned short* __restrict__ qfrag, unsigned short* __restrict__ pfrag) {
    __shared__ unsigned short sh[16 * 136];          // row stride 136 ushorts (272 B)
    int g = blockIdx.x;                              // 2544
    int t = threadIdx.x;
    int srow = t >> 4, c16 = t & 15;
    int d0 = c16 * 8;

    s16x8 v8 = (s16x8){0, 0, 0, 0, 0, 0, 0, 0};
    if (g < 240) {
        int mt = g % 5, qp = g / 5;
        int prow = mt * 16 + srow;
        if (prow < 70) {
            int hi = prow >= 35;
            int bq = qp * 2 + hi;
            int l = prow - hi * 35;
            size_t row = (size_t)bq * 35 + l;
            const f32x4* px = (const f32x4*)(x + row * D_ + d0);
            f32x4 v0 = px[0], v1 = px[1];
            const f32x4* pq = (const f32x4*)(ssq + (size_t)bq * D_ + d0);
            f32x4 q0 = pq[0], q1 = pq[1];
            f32x4 r0, r1;
#pragma unroll
            for (int j = 0; j < 4; j++) {
                r0[j] = rsqrtf(fmaxf(q0[j], 1e-24f));
                r1[j] = rsqrtf(fmaxf(q1[j], 1e-24f));
            }
            v8 = pack_bf16(v0 * r0, v1 * r1);
        }
    } else {
        int g2 = g - 240;
        int nt = g2 % 12, pbk = g2 / 12;
        int l = nt * 16 + srow;
        int lsrc = (l < LP && maskc[pbk * LP + l]) ? l : 0;
        size_t row = QROWS + (size_t)pbk * LP + lsrc;
        const f32x4* px = (const f32x4*)(x + row * D_ + d0);
        f32x4 v0 = px[0], v1 = px[1];
        const f32x4* pq = (const f32x4*)(ssq + (size_t)(96 + pbk) * D_ + d0);
        f32x4 q0 = pq[0], q1 = pq[1];
        f32x4 r0, r1;
#pragma unroll
        for (int j = 0; j < 4; j++) {
            r0[j] = rsqrtf(fmaxf(q0[j], 1e-24f));
            r1[j] = rsqrtf(fmaxf(q1[j], 1e-24f));
        }
        v8 = pack_bf16(v0 * r0, v1 * r1);
    }
    *(s16x8*)&sh[srow * 136 + d0] = v8;              // byte ofs = srow*272 + c16*16, aligned
    __syncthreads();

    int ks = t >> 6, lane = t & 63;
    int mm = lane & 15, quad = lane >> 4;
    s16x8 o = *(const s16x8*)&sh[mm * 136 + ks * 32 + quad * 8];
    unsigned short* dst = (g < 240) ? (qfrag + (size_t)g * 2048)
                                    : (pfrag + (size_t)(g - 240) * 2048);
    *(s16x8*)(dst + (size_t)t * 8) = o;              // 4 KB contiguous per block
}

// ---------------- interact v4: 768 blocks, 3 qp per wave, NO occupancy bound ------------
// __launch_bounds__(256) only: (256,3) capped VGPRs at 84 -> a[5][4] spilled to scratch
// (R11: 221 MB FETCH + 139 MB WRITE of spill traffic). Unbounded, allocator gets ~168
// VGPRs (3 waves/SIMD = the 48 KB LDS limit anyway) and fragments stay in registers.
__global__ __launch_bounds__(256) void interact_k(
    const unsigned short* __restrict__ qfrag, const unsigned short* __restrict__ pfrag,
    float* __restrict__ out) {
    __shared__ unsigned short plds[24576];           // 48 KB, shared by all 4 waves
    int wave = threadIdx.x >> 6, lane = threadIdx.x & 63;
    int b = blockIdx.x;                              // 768 blocks = 3/CU, one round
    int xcd = b & 7, i = b >> 3;                     // i in [0,96)
    int c = xcd * 24 + (i % 24);                     // [0,192), pinned per XCD
    int qg = i / 24;                                 // [0,4)
    int side = c / 96, pb = c - side * 96;
    int m = lane & 15, quad = lane >> 4;

    const unsigned short* pbase = pfrag + (size_t)c * 24576;

    // stage the 48 KB p-block (wave stages nt = wave*3 .. +3)
#pragma unroll
    for (int ntl = 0; ntl < 3; ntl++) {
        int nt = wave * 3 + ntl;
#pragma unroll
        for (int ks = 0; ks < 4; ks++)
            glds16(pbase + ((size_t)(nt * 4 + ks) * 64 + lane) * 8,
                   &plds[(size_t)(nt * 4 + ks) * 512]);
    }
    __syncthreads();                                 // drain staging

    const f32x4 zero4 = (f32x4){0.f, 0.f, 0.f, 0.f};

    for (int qpi = 0; qpi < 3; qpi++) {
        int qp = qg * 12 + wave * 3 + qpi;
        const unsigned short* qbase = qfrag + (size_t)qp * 10240;

        s16x8 a[5][4];
#pragma unroll
        for (int mt = 0; mt < 5; mt++)
#pragma unroll
            for (int ks = 0; ks < 4; ks++)
                a[mt][ks] = *(const s16x8*)(qbase + ((size_t)(mt * 4 + ks) * 64 + lane) * 8);

        float rmax[5][4];
#pragma unroll
        for (int mt = 0; mt < 5; mt++)
#pragma unroll
            for (int rr = 0; rr < 4; rr++) rmax[mt][rr] = NEGF;

        for (int nt = 0; nt < 12; nt++) {
            s16x8 bfr[4];
#pragma unroll
            for (int ks = 0; ks < 4; ks++)
                bfr[ks] = *(const s16x8*)&plds[((size_t)(nt * 4 + ks) * 64 + lane) * 8];
#pragma unroll
            for (int mt = 0; mt < 5; mt++) {
                f32x4 acc = __builtin_amdgcn_mfma_f32_16x16x32_bf16(a[mt][0], bfr[0], zero4, 0, 0, 0);
                acc = __builtin_amdgcn_mfma_f32_16x16x32_bf16(a[mt][1], bfr[1], acc, 0, 0, 0);
                acc = __builtin_amdgcn_mfma_f32_16x16x32_bf16(a[mt][2], bfr[2], acc, 0, 0, 0);
                acc = __builtin_amdgcn_mfma_f32_16x16x32_bf16(a[mt][3], bfr[3], acc, 0, 0, 0);
#pragma unroll
                for (int rr = 0; rr < 4; rr++)
                    rmax[mt][rr] = fmaxf(rmax[mt][rr], acc[rr]);
            }
        }

#pragma unroll
        for (int mt = 0; mt < 5; mt++)
#pragma unroll
            for (int rr = 0; rr < 4; rr++) {
                float v = rmax[mt][rr];
                v = fmaxf(v, __shfl_xor(v, 1));
                v = fmaxf(v, __shfl_xor(v, 2));
                v = fmaxf(v, __shfl_xor(v, 4));
                v = fmaxf(v, __shfl_xor(v, 8));
                rmax[mt][rr] = v;
            }
        float s0 = 0.f, s1 = 0.f;
#pragma unroll
        for (int mt = 0; mt < 5; mt++)
#pragma unroll
            for (int rr = 0; rr < 4; rr++) {
                int prow = mt * 16 + quad * 4 + rr;
                float v = rmax[mt][rr];
                if (prow < 35) s0 += v;
                else if (prow < 70) s1 += v;
            }
        s0 += __shfl_xor(s0, 16); s0 += __shfl_xor(s0, 32);
        s1 += __shfl_xor(s1, 16); s1 += __shfl_xor(s1, 32);
        if (lane == 0) {
            int qb0 = qp * 2, qb1 = qp * 2 + 1;
            out[(size_t)qb0 * (2 * B_) + side * B_ + pb] = s0;
            out[(size_t)qb1 * (2 * B_) + side * B_ + pb] = s1;
        }
    }
}

// ---------------- launch ----------------
extern "C" void kernel_launch(void* const* d_in, const int* in_sizes, int n_in,
                              void* d_out, int out_size, void* d_ws, size_t ws_size,
                              hipStream_t stream) {
    const float* qh   = (const float*)d_in[0];
    const float* ph   = (const float*)d_in[1];
    const float* nh   = (const float*)d_in[2];
    const float* W    = (const float*)d_in[3];
    const float* bias = (const float*)d_in[4];
    const void* pmask = d_in[5];
    const void* nmask = d_in[6];
    float* out = (float*)d_out;
    char* ws = (char*)d_ws;

    constexpr size_t CTRL_OFF  = 0;                          // 256 B
    constexpr size_t WTHI_OFF  = 256;                        // 196608 B
    constexpr size_t MASKC_OFF = WTHI_OFF + 196608;          // 34560 B -> ends 231424
    constexpr size_t SSQ_OFF   = 231424;                     // 147456 B
    constexpr size_t X_OFF     = SSQ_OFF + 147456;           // 19415040 B
    constexpr size_t QFRAG_OFF = X_OFF + (size_t)NROWS * D_ * 4;   // 983040 B
    constexpr size_t PFRAG_OFF = QFRAG_OFF + 983040;         // 9437184 B

    unsigned int* ctrl     = (unsigned int*)(ws + CTRL_OFF);
    unsigned short* wthi   = (unsigned short*)(ws + WTHI_OFF);
    unsigned char* maskc   = (unsigned char*)(ws + MASKC_OFF);
    float* ssq             = (float*)(ws + SSQ_OFF);
    float* x               = (float*)(ws + X_OFF);
    unsigned short* qfrag  = (unsigned short*)(ws + QFRAG_OFF);
    unsigned short* pfrag  = (unsigned short*)(ws + PFRAG_OFF);

    prep_k<<<193, 256, 0, stream>>>(W, wthi, (const unsigned int*)pmask, ctrl, ssq);
    proj_k<<<1185 + 135, 256, 0, stream>>>(qh, ph, nh, wthi, bias, x, ssq,
                                           pmask, nmask, ctrl, maskc);
    scatter_k<<<2544, 256, 0, stream>>>(x, ssq, maskc, qfrag, pfrag);
    interact_k<<<768, 256, 0, stream>>>(qfrag, pfrag, out);
}